// Round 4
// baseline (297.146 us; speedup 1.0000x reference)
//
#include <hip/hip_runtime.h>
#include <math.h>

// FourierConv2D: B=16,H=W=128,C=16,F=32. FFT 256x256, half-spectrum w in [0,129).
// rowFFT -> colFFT -> pointwise einsum -> col iFFT (crop y) -> Hermitian row iFFT (crop x, Re).
// FFT kernels: coalesced block-wide global<->LDS staging (2 __syncthreads total) +
// wave-synchronous register FFT (each 256-pt FFT in 16 lanes of one wave, row-local LDS).

constexpr int Bn = 16, Cc = 16, Ff = 32, Hh = 128, Ww = 128, Nn = 256, WH = 129;

#define DEVINL __device__ __forceinline__
DEVINL float2 f2(float a, float b) { return make_float2(a, b); }

#define CFENCE()   asm volatile("" ::: "memory")
#define LDSFENCE() asm volatile("s_waitcnt lgkmcnt(0)" ::: "memory")

// LDS geometry: 16 rows x 256 float2 = 32 KB exactly (5 blocks/CU).
// Row stride 256 float2 aliases banks across rows; de-alias with a per-row rotation.
DEVINL int ridx(int r, int e) { return r * 256 + ((e + 2 * r) & 255); }

// ---- in-register 16-point FFT, SGN=-1 forward, SGN=+1 inverse (unnormalized) ----
template<int SGN>
DEVINL void fft16r(float2 v[16]) {
  float2 t;
#define SW(a,b) { t = v[a]; v[a] = v[b]; v[b] = t; }
  SW(1, 8) SW(2, 4) SW(3, 12) SW(5, 10) SW(7, 14) SW(11, 13)
#undef SW
  const float C1 = 0.92387953251128674f, C2 = 0.70710678118654752f, C3 = 0.38268343236508977f;
  const float Ct[8] = {1.f, C1, C2, C3, 0.f, -C3, -C2, -C1};
  const float St[8] = {0.f, C3, C2, C1, 1.f, C1, C2, C3};
#pragma unroll
  for (int len = 2; len <= 16; len <<= 1) {
    const int half = len >> 1, ts = 16 / len;
#pragma unroll
    for (int i = 0; i < 16; i += len) {
#pragma unroll
      for (int j = 0; j < half; ++j) {
        const float wr = Ct[j * ts];
        const float wi = (SGN > 0) ? St[j * ts] : -St[j * ts];
        float2 b = v[i + j + half];
        float2 tt = f2(wr * b.x - wi * b.y, wr * b.y + wi * b.x);
        float2 a = v[i + j];
        v[i + j]        = f2(a.x + tt.x, a.y + tt.y);
        v[i + j + half] = f2(a.x - tt.x, a.y - tt.y);
      }
    }
  }
}

// ---- wave-synchronous 256-pt FFT core. entry: v[n1]=data[t+16*n1]; exit: v[k2]=X[t+16*k2].
// Uses only row r of LDS (owned by this 16-lane group); no block barriers.
template<int SGN>
DEVINL void fft256w(float2 v[16], float2* __restrict__ lds, int r, int t) {
  fft16r<SGN>(v);
  float sb, cb;   // twiddle chain w_k = exp(SGN*2pi i*t*k/256)
  __sincosf((SGN > 0 ? 0.024543692606170259f : -0.024543692606170259f) * (float)t, &sb, &cb);
  float wr = cb, wi = sb;
#pragma unroll
  for (int k = 1; k < 16; ++k) {
    float2 a = v[k];
    v[k] = f2(a.x * wr - a.y * wi, a.x * wi + a.y * wr);
    float nr = wr * cb - wi * sb, ni = wr * sb + wi * cb;
    wr = nr; wi = ni;
  }
  CFENCE();
#pragma unroll
  for (int k = 0; k < 16; ++k) lds[ridx(r, t * 16 + ((k + t) & 15))] = v[k];  // rotated: conflict-free
  LDSFENCE();
#pragma unroll
  for (int n2 = 0; n2 < 16; ++n2) v[n2] = lds[ridx(r, n2 * 16 + ((t + n2) & 15))];
  CFENCE();
  fft16r<SGN>(v);
}

// ---- K1: per (b,y): 16 row FFTs over x (zero-pad 128->256), keep w in [0,129) ----
// R layout: [b][w][y][c]
__global__ __launch_bounds__(256, 5) void k1_rowfft(const float* __restrict__ img, float2* __restrict__ R) {
  __shared__ float2 lds[16 * 256];
  const int tid = threadIdx.x, r = tid >> 4, t = tid & 15;
  const int y = blockIdx.x, b = blockIdx.y;
  const float* ip = img + ((size_t)(b * Hh + y) * Ww) * Cc;
  for (int i = tid; i < Ww * Cc; i += 256) { int x = i >> 4, c = i & 15; lds[ridx(c, x)] = f2(ip[i], 0.f); }
  __syncthreads();
  float2 v[16];
#pragma unroll
  for (int j = 0; j < 8; ++j) v[j] = lds[ridx(r, t + 16 * j)];
#pragma unroll
  for (int j = 8; j < 16; ++j) v[j] = f2(0.f, 0.f);
  CFENCE();
  fft256w<-1>(v, lds, r, t);
#pragma unroll
  for (int k = 0; k < 8; ++k) lds[ridx(r, t + 16 * k)] = v[k];
  if (t == 0) lds[ridx(r, 128)] = v[8];
  __syncthreads();
  float2* rp = R + (size_t)b * WH * Hh * Cc + (size_t)y * Cc;
  for (int i = tid; i < WH * Cc; i += 256) {
    int w = i >> 4, c = i & 15;
    rp[(size_t)w * Hh * Cc + c] = lds[ridx(c, w)];
  }
}

// ---- K2: per (b,w): 16 column FFTs over y (zero-pad 128->256) ----
// Fimg layout: [h][w][b][c]
__global__ __launch_bounds__(256, 5) void k2_colfft(const float2* __restrict__ R, float2* __restrict__ Fimg) {
  __shared__ float2 lds[16 * 256];
  const int tid = threadIdx.x, r = tid >> 4, t = tid & 15;
  const int w = blockIdx.x, b = blockIdx.y;
  const float2* rp = R + ((size_t)(b * WH + w) * Hh) * Cc;
  for (int i = tid; i < Hh * Cc; i += 256) { int y = i >> 4, c = i & 15; lds[ridx(c, y)] = rp[i]; }
  __syncthreads();
  float2 v[16];
#pragma unroll
  for (int j = 0; j < 8; ++j) v[j] = lds[ridx(r, t + 16 * j)];
#pragma unroll
  for (int j = 8; j < 16; ++j) v[j] = f2(0.f, 0.f);
  CFENCE();
  fft256w<-1>(v, lds, r, t);
#pragma unroll
  for (int k2 = 0; k2 < 16; ++k2) lds[ridx(r, t + 16 * k2)] = v[k2];
  __syncthreads();
  float2* fp = Fimg + (size_t)w * 256 + b * 16;
  for (int i = tid; i < Nn * Cc; i += 256) {
    int h = i >> 4, c = i & 15;
    fp[(size_t)h * WH * 256 + c] = lds[ridx(c, h)];
  }
}

// ---- K3: per (h,w): out_f[b,f] = sum_c Fimg[b,c] * (Kr[f,c] + i Ki[f,c]) ----
// 8 h-points per block, LDS double-buffered with register prefetch. OF layout: [w][h][b][f]
constexpr int GP = 8;
__global__ __launch_bounds__(256) void k3_mul(const float2* __restrict__ Fimg, const float* __restrict__ Kr,
                                              const float* __restrict__ Ki, float2* __restrict__ OF) {
  __shared__ float2 A[2][256];
  __shared__ float kr[2][16][33];
  __shared__ float ki[2][16][33];
  const int tid = threadIdx.x;
  const int w = blockIdx.x, h0 = blockIdx.y * GP;
  const int b0 = tid >> 5;
  const int f0 = tid & 31;
  const int cS = tid & 15, fS = tid >> 4;

  float2 aReg;
  float krA, krB, kiA, kiB;

  auto load_regs = [&](int g) {
    const size_t base = (size_t)(h0 + g) * WH + w;
    aReg = Fimg[base * 256 + tid];
    const size_t ko = base * 512;
    krA = Kr[ko + tid]; krB = Kr[ko + tid + 256];
    kiA = Ki[ko + tid]; kiB = Ki[ko + tid + 256];
  };
  auto write_lds = [&](int bb) {
    A[bb][tid] = aReg;
    kr[bb][cS][fS] = krA;  kr[bb][cS][fS + 16] = krB;
    ki[bb][cS][fS] = kiA;  ki[bb][cS][fS + 16] = kiB;
  };

  load_regs(0);
  write_lds(0);
#pragma unroll
  for (int g = 0; g < GP; ++g) {
    const int cur = g & 1;
    if (g + 1 < GP) load_regs(g + 1);
    __syncthreads();
    float2 acc0 = f2(0.f, 0.f), acc1 = f2(0.f, 0.f);
#pragma unroll
    for (int c = 0; c < 16; ++c) {
      const float krv = kr[cur][c][f0], kiv = ki[cur][c][f0];
      const float2 a0 = A[cur][b0 * 16 + c];
      const float2 a1 = A[cur][(b0 + 8) * 16 + c];
      acc0.x += a0.x * krv - a0.y * kiv;  acc0.y += a0.x * kiv + a0.y * krv;
      acc1.x += a1.x * krv - a1.y * kiv;  acc1.y += a1.x * kiv + a1.y * krv;
    }
    float2* op = OF + ((size_t)w * 256 + (h0 + g)) * 512;
    op[tid] = acc0;
    op[tid + 256] = acc1;
    if (g + 1 < GP) write_lds(cur ^ 1);
  }
}

// ---- K4: per (b,w,fg): 16 inverse column FFTs over h; store y' = h-63 in [0,128) ----
// T layout: [b][y'][w][f]
__global__ __launch_bounds__(256, 5) void k4_colifft(const float2* __restrict__ OF, float2* __restrict__ T) {
  __shared__ float2 lds[16 * 256];
  const int tid = threadIdx.x, r = tid >> 4, t = tid & 15;
  const int w = blockIdx.x, b = blockIdx.y, fg = blockIdx.z;
  const float2* ofp = OF + (size_t)w * 256 * 512 + b * 32 + fg * 16;
  for (int i = tid; i < Nn * 16; i += 256) {
    int h = i >> 4, fl = i & 15;
    lds[ridx(fl, h)] = ofp[(size_t)h * 512 + fl];
  }
  __syncthreads();
  float2 v[16];
#pragma unroll
  for (int j = 0; j < 16; ++j) v[j] = lds[ridx(r, t + 16 * j)];
  CFENCE();
  fft256w<1>(v, lds, r, t);
#pragma unroll
  for (int k2 = 3; k2 < 12; ++k2) lds[ridx(r, t + 16 * k2)] = v[k2];  // elems 48..191 (need 63..190)
  __syncthreads();
  float2* tp = T + (size_t)b * Hh * WH * Ff + (size_t)w * Ff + fg * 16;
  for (int i = tid; i < Hh * 16; i += 256) {
    int yp = i >> 4, fl = i & 15;
    tp[(size_t)yp * WH * Ff + fl] = lds[ridx(fl, 63 + yp)];
  }
}

// ---- K5: per (b,y',fg): Hermitian-extend w-spectrum, inverse FFT, Re, scale, +bias, crop x ----
__global__ __launch_bounds__(256, 5) void k5_rowifft(const float2* __restrict__ T, const float* __restrict__ bias,
                                                     float* __restrict__ out) {
  __shared__ float2 lds[16 * 256];
  const int tid = threadIdx.x, r = tid >> 4, t = tid & 15;
  const int yp = blockIdx.x, b = blockIdx.y, fg = blockIdx.z;
  const float2* tp = T + ((size_t)(b * Hh + yp) * WH) * Ff + fg * 16;
  for (int i = tid; i < WH * 16; i += 256) {
    int w = i >> 4, fl = i & 15;
    lds[ridx(fl, w)] = tp[(size_t)w * Ff + fl];
  }
  __syncthreads();
  float2 v[16];
#pragma unroll
  for (int n1 = 0; n1 < 16; ++n1) {          // Hermitian mirror folded into load
    const int c = t + 16 * n1;
    if (c <= 128) v[n1] = lds[ridx(r, c)];
    else { float2 z = lds[ridx(r, 256 - c)]; v[n1] = f2(z.x, -z.y); }
  }
  CFENCE();
  fft256w<1>(v, lds, r, t);
#pragma unroll
  for (int k2 = 3; k2 < 12; ++k2) lds[ridx(r, t + 16 * k2)] = v[k2];
  __syncthreads();
  const float sc = 1.f / 65536.f;
  const float bv = bias[fg * 16 + (tid & 15)];
  float* op = out + ((size_t)(b * Hh + yp) * Ww) * Ff + fg * 16;
  for (int i = tid; i < Ww * 16; i += 256) {
    int x = i >> 4, fl = i & 15;
    op[(size_t)x * Ff + fl] = lds[ridx(fl, 63 + x)].x * sc + bv;
  }
}

extern "C" void kernel_launch(void* const* d_in, const int* in_sizes, int n_in,
                              void* d_out, int out_size, void* d_ws, size_t ws_size,
                              hipStream_t stream) {
  const float* img  = (const float*)d_in[0];
  const float* kr   = (const float*)d_in[1];
  const float* ki   = (const float*)d_in[2];
  const float* bias = (const float*)d_in[3];
  float* out = (float*)d_out;

  char* ws = (char*)d_ws;
  // region layout (lifetime-overlapped):
  //   [0, 67.6MB):     Fimg (K2->K3), later T (K4->K5)
  //   [67.6MB, 203MB): OF (K3->K4);  R (K1->K2) aliases its head (dead before K3)
  const size_t szF = (size_t)Nn * WH * Bn * Cc * sizeof(float2);   // 67,633,152
  float2* Fimg = (float2*)ws;
  float2* T    = (float2*)ws;
  float2* OF   = (float2*)(ws + szF);
  float2* R    = (float2*)(ws + szF);

  k1_rowfft <<<dim3(Hh, Bn),      256, 0, stream>>>(img, R);
  k2_colfft <<<dim3(WH, Bn),      256, 0, stream>>>(R, Fimg);
  k3_mul    <<<dim3(WH, Nn / GP), 256, 0, stream>>>(Fimg, kr, ki, OF);
  k4_colifft<<<dim3(WH, Bn, 2),   256, 0, stream>>>(OF, T);
  k5_rowifft<<<dim3(Hh, Bn, 2),   256, 0, stream>>>(T, bias, out);
}

// Round 5
// 203.017 us; speedup vs baseline: 1.4637x; 1.4637x over previous
//
#include <hip/hip_runtime.h>
#include <math.h>

// FourierConv2D: B=16,H=W=128,C=16,F=32. FFT 256x256, half-spectrum w in [0,129).
// rowFFT -> colFFT -> pointwise einsum -> col iFFT (crop y) -> Hermitian row iFFT (crop x, Re).
// v5: v2 skeleton (coalesced block staging, 2 block barriers) + register FFT middle with ONE
// rotated LDS transpose per FFT (16-lane group owns its LDS row; same-wave DS ops are in-order,
// so no internal barriers, no inline asm). Independent __sincosf twiddles (no table, no chain).
// LDS = exactly 32KB -> 5 blocks/CU; (e+r)&255 row map keeps every phase at the b64 bank floor.

constexpr int Bn = 16, Cc = 16, Ff = 32, Hh = 128, Ww = 128, Nn = 256, WH = 129;

#define DEVINL __device__ __forceinline__
DEVINL float2 f2(float a, float b) { return make_float2(a, b); }

// LDS map: row r (owned by 16-lane group r), element e in [0,256). 16*256 float2 = 32 KB.
DEVINL int IDX(int r, int e) { return r * 256 + ((e + r) & 255); }

// ---- in-register 16-point FFT, SGN=-1 forward, SGN=+1 inverse (unnormalized) ----
template<int SGN>
DEVINL void fft16r(float2 v[16]) {
  float2 t;
#define SW(a,b) { t = v[a]; v[a] = v[b]; v[b] = t; }
  SW(1, 8) SW(2, 4) SW(3, 12) SW(5, 10) SW(7, 14) SW(11, 13)
#undef SW
  const float C1 = 0.92387953251128674f, C2 = 0.70710678118654752f, C3 = 0.38268343236508977f;
  const float Ct[8] = {1.f, C1, C2, C3, 0.f, -C3, -C2, -C1};
  const float St[8] = {0.f, C3, C2, C1, 1.f, C1, C2, C3};
#pragma unroll
  for (int len = 2; len <= 16; len <<= 1) {
    const int half = len >> 1, ts = 16 / len;
#pragma unroll
    for (int i = 0; i < 16; i += len) {
#pragma unroll
      for (int j = 0; j < half; ++j) {
        const float wr = Ct[j * ts];
        const float wi = (SGN > 0) ? St[j * ts] : -St[j * ts];
        float2 b = v[i + j + half];
        float2 tt = f2(wr * b.x - wi * b.y, wr * b.y + wi * b.x);
        float2 a = v[i + j];
        v[i + j]        = f2(a.x + tt.x, a.y + tt.y);
        v[i + j + half] = f2(a.x - tt.x, a.y - tt.y);
      }
    }
  }
}

// ---- 256-pt FFT middle: entry v[n1] = x[t + 16*n1]; exit v[k2] = X[t + 16*k2].
// Touches ONLY row r of LDS (single 16-lane group, single wave): no block barriers needed.
template<int SGN>
DEVINL void fft256_mid(float2 v[16], float2* __restrict__ lds, int r, int t) {
  fft16r<SGN>(v);
  const float unit = (SGN > 0) ? 0.024543692606170259f : -0.024543692606170259f;  // 2*pi/256
#pragma unroll
  for (int k = 1; k < 16; ++k) {               // independent twiddles: v[k] *= exp(i*unit*t*k)
    float sb, cb;
    __sincosf(unit * (float)(t * k), &sb, &cb);
    float2 a = v[k];
    v[k] = f2(a.x * cb - a.y * sb, a.x * sb + a.y * cb);
  }
#pragma unroll
  for (int k = 0; k < 16; ++k) lds[IDX(r, t * 16 + ((k + t) & 15))] = v[k];   // rotated: bank floor
#pragma unroll
  for (int n2 = 0; n2 < 16; ++n2) v[n2] = lds[IDX(r, n2 * 16 + ((t + n2) & 15))];
  fft16r<SGN>(v);
}

// ---- K1: per (b,y): 16 row FFTs over x (zero-pad 128->256 in registers), keep w in [0,129) ----
// R layout: [b][w][y][c]
__global__ __launch_bounds__(256) void k1_rowfft(const float* __restrict__ img, float2* __restrict__ R) {
  __shared__ float2 lds[16 * 256];
  const int tid = threadIdx.x, r = tid >> 4, t = tid & 15;
  const int y = blockIdx.x, b = blockIdx.y;
  const float* ip = img + ((size_t)(b * Hh + y) * Ww) * Cc;
  for (int i = tid; i < Ww * Cc; i += 256) { int x = i >> 4, c = i & 15; lds[IDX(c, x)] = f2(ip[i], 0.f); }
  __syncthreads();
  float2 v[16];
#pragma unroll
  for (int j = 0; j < 8; ++j) v[j] = lds[IDX(r, t + 16 * j)];
#pragma unroll
  for (int j = 8; j < 16; ++j) v[j] = f2(0.f, 0.f);
  fft256_mid<-1>(v, lds, r, t);
#pragma unroll
  for (int k = 0; k < 8; ++k) lds[IDX(r, t + 16 * k)] = v[k];
  if (t == 0) lds[IDX(r, 128)] = v[8];
  __syncthreads();
  float2* rp = R + (size_t)b * WH * Hh * Cc + (size_t)y * Cc;
  for (int i = tid; i < WH * Cc; i += 256) {
    int w = i >> 4, c = i & 15;
    rp[(size_t)w * Hh * Cc + c] = lds[IDX(c, w)];
  }
}

// ---- K2: per (b,w): 16 column FFTs over y (zero-pad 128->256 in registers) ----
// Fimg layout: [h][w][b][c]
__global__ __launch_bounds__(256) void k2_colfft(const float2* __restrict__ R, float2* __restrict__ Fimg) {
  __shared__ float2 lds[16 * 256];
  const int tid = threadIdx.x, r = tid >> 4, t = tid & 15;
  const int w = blockIdx.x, b = blockIdx.y;
  const float2* rp = R + ((size_t)(b * WH + w) * Hh) * Cc;
  for (int i = tid; i < Hh * Cc; i += 256) { int y = i >> 4, c = i & 15; lds[IDX(c, y)] = rp[i]; }
  __syncthreads();
  float2 v[16];
#pragma unroll
  for (int j = 0; j < 8; ++j) v[j] = lds[IDX(r, t + 16 * j)];
#pragma unroll
  for (int j = 8; j < 16; ++j) v[j] = f2(0.f, 0.f);
  fft256_mid<-1>(v, lds, r, t);
#pragma unroll
  for (int k2 = 0; k2 < 16; ++k2) lds[IDX(r, t + 16 * k2)] = v[k2];
  __syncthreads();
  float2* fp = Fimg + (size_t)w * 256 + b * 16;
  for (int i = tid; i < Nn * Cc; i += 256) {
    int h = i >> 4, c = i & 15;
    fp[(size_t)h * WH * 256 + c] = lds[IDX(c, h)];
  }
}

// ---- K3: per (h,w): out_f[b,f] = sum_c Fimg[b,c] * (Kr[f,c] + i Ki[f,c]) ----
// 8 h-points per block, LDS double-buffered with register prefetch. OF layout: [w][h][b][f]
constexpr int GP = 8;
__global__ __launch_bounds__(256) void k3_mul(const float2* __restrict__ Fimg, const float* __restrict__ Kr,
                                              const float* __restrict__ Ki, float2* __restrict__ OF) {
  __shared__ float2 A[2][256];
  __shared__ float kr[2][16][33];
  __shared__ float ki[2][16][33];
  const int tid = threadIdx.x;
  const int w = blockIdx.x, h0 = blockIdx.y * GP;
  const int b0 = tid >> 5;
  const int f0 = tid & 31;
  const int cS = tid & 15, fS = tid >> 4;

  float2 aReg;
  float krA, krB, kiA, kiB;

  auto load_regs = [&](int g) {
    const size_t base = (size_t)(h0 + g) * WH + w;
    aReg = Fimg[base * 256 + tid];
    const size_t ko = base * 512;
    krA = Kr[ko + tid]; krB = Kr[ko + tid + 256];
    kiA = Ki[ko + tid]; kiB = Ki[ko + tid + 256];
  };
  auto write_lds = [&](int bb) {
    A[bb][tid] = aReg;
    kr[bb][cS][fS] = krA;  kr[bb][cS][fS + 16] = krB;
    ki[bb][cS][fS] = kiA;  ki[bb][cS][fS + 16] = kiB;
  };

  load_regs(0);
  write_lds(0);
#pragma unroll
  for (int g = 0; g < GP; ++g) {
    const int cur = g & 1;
    if (g + 1 < GP) load_regs(g + 1);
    __syncthreads();
    float2 acc0 = f2(0.f, 0.f), acc1 = f2(0.f, 0.f);
#pragma unroll
    for (int c = 0; c < 16; ++c) {
      const float krv = kr[cur][c][f0], kiv = ki[cur][c][f0];
      const float2 a0 = A[cur][b0 * 16 + c];
      const float2 a1 = A[cur][(b0 + 8) * 16 + c];
      acc0.x += a0.x * krv - a0.y * kiv;  acc0.y += a0.x * kiv + a0.y * krv;
      acc1.x += a1.x * krv - a1.y * kiv;  acc1.y += a1.x * kiv + a1.y * krv;
    }
    float2* op = OF + ((size_t)w * 256 + (h0 + g)) * 512;
    op[tid] = acc0;
    op[tid + 256] = acc1;
    if (g + 1 < GP) write_lds(cur ^ 1);
  }
}

// ---- K4: per (b,w,fg): 16 inverse column FFTs over h; store y' = h-63 in [0,128) ----
// T layout: [b][y'][w][f]
__global__ __launch_bounds__(256) void k4_colifft(const float2* __restrict__ OF, float2* __restrict__ T) {
  __shared__ float2 lds[16 * 256];
  const int tid = threadIdx.x, r = tid >> 4, t = tid & 15;
  const int w = blockIdx.x, b = blockIdx.y, fg = blockIdx.z;
  const float2* ofp = OF + (size_t)w * 256 * 512 + b * 32 + fg * 16;
  for (int i = tid; i < Nn * 16; i += 256) {
    int h = i >> 4, fl = i & 15;
    lds[IDX(fl, h)] = ofp[(size_t)h * 512 + fl];
  }
  __syncthreads();
  float2 v[16];
#pragma unroll
  for (int j = 0; j < 16; ++j) v[j] = lds[IDX(r, t + 16 * j)];
  fft256_mid<1>(v, lds, r, t);
#pragma unroll
  for (int k2 = 3; k2 < 12; ++k2) lds[IDX(r, t + 16 * k2)] = v[k2];  // elems 48..191 cover 63..190
  __syncthreads();
  float2* tp = T + (size_t)b * Hh * WH * Ff + (size_t)w * Ff + fg * 16;
  for (int i = tid; i < Hh * 16; i += 256) {
    int yp = i >> 4, fl = i & 15;
    tp[(size_t)yp * WH * Ff + fl] = lds[IDX(fl, 63 + yp)];
  }
}

// ---- K5: per (b,y',fg): Hermitian-extend w-spectrum, inverse FFT, Re, scale, +bias, crop x ----
__global__ __launch_bounds__(256) void k5_rowifft(const float2* __restrict__ T, const float* __restrict__ bias,
                                                  float* __restrict__ out) {
  __shared__ float2 lds[16 * 256];
  const int tid = threadIdx.x, r = tid >> 4, t = tid & 15;
  const int yp = blockIdx.x, b = blockIdx.y, fg = blockIdx.z;
  const float2* tp = T + ((size_t)(b * Hh + yp) * WH) * Ff + fg * 16;
  for (int i = tid; i < WH * 16; i += 256) {
    int w = i >> 4, fl = i & 15;
    lds[IDX(fl, w)] = tp[(size_t)w * Ff + fl];
  }
  __syncthreads();
  float2 v[16];
#pragma unroll
  for (int n1 = 0; n1 < 16; ++n1) {            // Hermitian mirror folded into register load
    const int c = t + 16 * n1;
    if (c <= 128) v[n1] = lds[IDX(r, c)];
    else { float2 z = lds[IDX(r, 256 - c)]; v[n1] = f2(z.x, -z.y); }
  }
  fft256_mid<1>(v, lds, r, t);
#pragma unroll
  for (int k2 = 3; k2 < 12; ++k2) lds[IDX(r, t + 16 * k2)] = v[k2];
  __syncthreads();
  const float sc = 1.f / 65536.f;
  const float bv = bias[fg * 16 + (tid & 15)];
  float* op = out + ((size_t)(b * Hh + yp) * Ww) * Ff + fg * 16;
  for (int i = tid; i < Ww * 16; i += 256) {
    int x = i >> 4, fl = i & 15;
    op[(size_t)x * Ff + fl] = lds[IDX(fl, 63 + x)].x * sc + bv;
  }
}

extern "C" void kernel_launch(void* const* d_in, const int* in_sizes, int n_in,
                              void* d_out, int out_size, void* d_ws, size_t ws_size,
                              hipStream_t stream) {
  const float* img  = (const float*)d_in[0];
  const float* kr   = (const float*)d_in[1];
  const float* ki   = (const float*)d_in[2];
  const float* bias = (const float*)d_in[3];
  float* out = (float*)d_out;

  char* ws = (char*)d_ws;
  // region layout (lifetime-overlapped):
  //   [0, 67.6MB):     Fimg (K2->K3), later T (K4->K5)
  //   [67.6MB, 203MB): OF (K3->K4);  R (K1->K2) aliases its head (dead before K3)
  const size_t szF = (size_t)Nn * WH * Bn * Cc * sizeof(float2);   // 67,633,152
  float2* Fimg = (float2*)ws;
  float2* T    = (float2*)ws;
  float2* OF   = (float2*)(ws + szF);
  float2* R    = (float2*)(ws + szF);

  k1_rowfft <<<dim3(Hh, Bn),      256, 0, stream>>>(img, R);
  k2_colfft <<<dim3(WH, Bn),      256, 0, stream>>>(R, Fimg);
  k3_mul    <<<dim3(WH, Nn / GP), 256, 0, stream>>>(Fimg, kr, ki, OF);
  k4_colifft<<<dim3(WH, Bn, 2),   256, 0, stream>>>(OF, T);
  k5_rowifft<<<dim3(Hh, Bn, 2),   256, 0, stream>>>(T, bias, out);
}

// Round 6
// 179.874 us; speedup vs baseline: 1.6520x; 1.1287x over previous
//
#include <hip/hip_runtime.h>
#include <math.h>

// FourierConv2D: B=16,H=W=128,C=16,F=32. FFT 256x256, half-spectrum w in [0,129).
// rowFFT -> colFFT -> pointwise einsum -> col iFFT (crop y) -> Hermitian row iFFT (crop x, Re).
// v6: v5 FFT kernels; k3 re-tiled as one-wave-per-point (no barriers, b128 LDS reads,
// 4b x 2f complex tile per lane); Fimg and OF stored as bf16 pairs (halve traffic).

constexpr int Bn = 16, Cc = 16, Ff = 32, Hh = 128, Ww = 128, Nn = 256, WH = 129;

#define DEVINL __device__ __forceinline__
DEVINL float2 f2(float a, float b) { return make_float2(a, b); }

// bf16 pack/unpack (round-half-up; spectra tolerate 0.4% rel noise, spreads ~1/sqrt(N) in iFFT)
DEVINL unsigned short f2bf(float f) { unsigned u = __float_as_uint(f); return (unsigned short)((u + 0x8000u) >> 16); }
DEVINL float bf2f(unsigned short h) { return __uint_as_float(((unsigned)h) << 16); }

// LDS map for FFT kernels: row r, element e in [0,256). 16*256 float2 = 32 KB.
DEVINL int IDX(int r, int e) { return r * 256 + ((e + r) & 255); }

// ---- in-register 16-point FFT, SGN=-1 forward, SGN=+1 inverse (unnormalized) ----
template<int SGN>
DEVINL void fft16r(float2 v[16]) {
  float2 t;
#define SW(a,b) { t = v[a]; v[a] = v[b]; v[b] = t; }
  SW(1, 8) SW(2, 4) SW(3, 12) SW(5, 10) SW(7, 14) SW(11, 13)
#undef SW
  const float C1 = 0.92387953251128674f, C2 = 0.70710678118654752f, C3 = 0.38268343236508977f;
  const float Ct[8] = {1.f, C1, C2, C3, 0.f, -C3, -C2, -C1};
  const float St[8] = {0.f, C3, C2, C1, 1.f, C1, C2, C3};
#pragma unroll
  for (int len = 2; len <= 16; len <<= 1) {
    const int half = len >> 1, ts = 16 / len;
#pragma unroll
    for (int i = 0; i < 16; i += len) {
#pragma unroll
      for (int j = 0; j < half; ++j) {
        const float wr = Ct[j * ts];
        const float wi = (SGN > 0) ? St[j * ts] : -St[j * ts];
        float2 b = v[i + j + half];
        float2 tt = f2(wr * b.x - wi * b.y, wr * b.y + wi * b.x);
        float2 a = v[i + j];
        v[i + j]        = f2(a.x + tt.x, a.y + tt.y);
        v[i + j + half] = f2(a.x - tt.x, a.y - tt.y);
      }
    }
  }
}

// ---- 256-pt FFT middle: entry v[n1] = x[t + 16*n1]; exit v[k2] = X[t + 16*k2].
// Touches ONLY row r of LDS (single 16-lane group, single wave): no block barriers needed.
template<int SGN>
DEVINL void fft256_mid(float2 v[16], float2* __restrict__ lds, int r, int t) {
  fft16r<SGN>(v);
  const float unit = (SGN > 0) ? 0.024543692606170259f : -0.024543692606170259f;  // 2*pi/256
#pragma unroll
  for (int k = 1; k < 16; ++k) {
    float sb, cb;
    __sincosf(unit * (float)(t * k), &sb, &cb);
    float2 a = v[k];
    v[k] = f2(a.x * cb - a.y * sb, a.x * sb + a.y * cb);
  }
#pragma unroll
  for (int k = 0; k < 16; ++k) lds[IDX(r, t * 16 + ((k + t) & 15))] = v[k];
#pragma unroll
  for (int n2 = 0; n2 < 16; ++n2) v[n2] = lds[IDX(r, n2 * 16 + ((t + n2) & 15))];
  fft16r<SGN>(v);
}

// ---- K1: per (b,y): 16 row FFTs over x (zero-pad 128->256 in registers), keep w in [0,129) ----
// R layout: [b][w][y][c]  (f32)
__global__ __launch_bounds__(256) void k1_rowfft(const float* __restrict__ img, float2* __restrict__ R) {
  __shared__ float2 lds[16 * 256];
  const int tid = threadIdx.x, r = tid >> 4, t = tid & 15;
  const int y = blockIdx.x, b = blockIdx.y;
  const float* ip = img + ((size_t)(b * Hh + y) * Ww) * Cc;
  for (int i = tid; i < Ww * Cc; i += 256) { int x = i >> 4, c = i & 15; lds[IDX(c, x)] = f2(ip[i], 0.f); }
  __syncthreads();
  float2 v[16];
#pragma unroll
  for (int j = 0; j < 8; ++j) v[j] = lds[IDX(r, t + 16 * j)];
#pragma unroll
  for (int j = 8; j < 16; ++j) v[j] = f2(0.f, 0.f);
  fft256_mid<-1>(v, lds, r, t);
#pragma unroll
  for (int k = 0; k < 8; ++k) lds[IDX(r, t + 16 * k)] = v[k];
  if (t == 0) lds[IDX(r, 128)] = v[8];
  __syncthreads();
  float2* rp = R + (size_t)b * WH * Hh * Cc + (size_t)y * Cc;
  for (int i = tid; i < WH * Cc; i += 256) {
    int w = i >> 4, c = i & 15;
    rp[(size_t)w * Hh * Cc + c] = lds[IDX(c, w)];
  }
}

// ---- K2: per (b,w): 16 column FFTs over y (zero-pad 128->256 in registers) ----
// Fimg layout: [h][w][b][c]  (bf16 pairs)
__global__ __launch_bounds__(256) void k2_colfft(const float2* __restrict__ R, ushort2* __restrict__ Fimg) {
  __shared__ float2 lds[16 * 256];
  const int tid = threadIdx.x, r = tid >> 4, t = tid & 15;
  const int w = blockIdx.x, b = blockIdx.y;
  const float2* rp = R + ((size_t)(b * WH + w) * Hh) * Cc;
  for (int i = tid; i < Hh * Cc; i += 256) { int y = i >> 4, c = i & 15; lds[IDX(c, y)] = rp[i]; }
  __syncthreads();
  float2 v[16];
#pragma unroll
  for (int j = 0; j < 8; ++j) v[j] = lds[IDX(r, t + 16 * j)];
#pragma unroll
  for (int j = 8; j < 16; ++j) v[j] = f2(0.f, 0.f);
  fft256_mid<-1>(v, lds, r, t);
#pragma unroll
  for (int k2 = 0; k2 < 16; ++k2) lds[IDX(r, t + 16 * k2)] = v[k2];
  __syncthreads();
  ushort2* fp = Fimg + (size_t)w * 256 + b * 16;
  for (int i = tid; i < Nn * Cc; i += 256) {
    int h = i >> 4, c = i & 15;
    float2 z = lds[IDX(c, h)];
    fp[(size_t)h * WH * 256 + c] = make_ushort2(f2bf(z.x), f2bf(z.y));
  }
}

// ---- K3: per (h,w): out_f[b,f] = sum_c Fimg[b,c] * (Kr[f,c] + i Ki[f,c]) ----
// v6: one WAVE per point (no block barriers). Lane tile: 4 b x 2 f complex outputs.
// LDS per wave: A[2][16][16] f2 (point's Fimg, f32) + K[2][32][18] f2 (packed (kr,ki), padded).
// Inner loop: b128 LDS reads (2 c per read). 4 points per wave, register-prefetch dbuf.
// OF layout: [w][h][b][f]  (bf16 pairs)
constexpr int PPW = 4;                  // points per wave
constexpr int GP = 4 * PPW;             // points per block (4 waves)
__global__ __launch_bounds__(256) void k3_mul(const ushort2* __restrict__ Fimg, const float* __restrict__ Kr,
                                              const float* __restrict__ Ki, ushort2* __restrict__ OF) {
  __shared__ float2 Abuf[4][2][16][16];   // [wave][buf][b][c]          16 KB
  __shared__ float2 Kbuf[4][2][32][18];   // [wave][buf][f][c] (pad 18) 36 KB  -> 52 KB total, 3 blk/CU
  const int tid = threadIdx.x;
  const int wv = tid >> 6, ln = tid & 63;
  const int w = blockIdx.x, h0 = blockIdx.y * GP + wv * PPW;
  const int bq = ln >> 4, fq = ln & 15;

  ushort2 aU[4];
  float   krR[8], kiR[8];

  auto load_regs = [&](int g) {                       // global -> regs for point h0+g
    const size_t base = (size_t)(h0 + g) * WH + w;
    const ushort2* ap = Fimg + base * 256;
#pragma unroll
    for (int k = 0; k < 4; ++k) aU[k] = ap[ln + 64 * k];
    const float* krp = Kr + base * 512;
    const float* kip = Ki + base * 512;
#pragma unroll
    for (int k = 0; k < 8; ++k) { krR[k] = krp[ln + 64 * k]; kiR[k] = kip[ln + 64 * k]; }
  };
  auto write_lds = [&](int bb) {                      // regs -> this wave's LDS buffer bb
#pragma unroll
    for (int k = 0; k < 4; ++k) {
      int j = ln + 64 * k;
      Abuf[wv][bb][j >> 4][j & 15] = f2(bf2f(aU[k].x), bf2f(aU[k].y));
    }
#pragma unroll
    for (int k = 0; k < 8; ++k) {
      int j = ln + 64 * k;
      Kbuf[wv][bb][j >> 4][j & 15] = f2(krR[k], kiR[k]);
    }
  };
  auto compute_store = [&](int bb, int g) {
    float2 acc[4][2];
#pragma unroll
    for (int i = 0; i < 4; ++i) { acc[i][0] = f2(0.f, 0.f); acc[i][1] = f2(0.f, 0.f); }
#pragma unroll
    for (int cc = 0; cc < 16; cc += 2) {              // 2 c per step via b128
      const float4 k0 = *(const float4*)&Kbuf[wv][bb][fq][cc];        // (kr,ki, kr',ki')
      const float4 k1 = *(const float4*)&Kbuf[wv][bb][fq + 16][cc];
#pragma unroll
      for (int i = 0; i < 4; ++i) {
        const float4 a = *(const float4*)&Abuf[wv][bb][bq + 4 * i][cc]; // (ar,ai, ar',ai')
        acc[i][0].x += a.x * k0.x - a.y * k0.y;  acc[i][0].y += a.x * k0.y + a.y * k0.x;
        acc[i][0].x += a.z * k0.z - a.w * k0.w;  acc[i][0].y += a.z * k0.w + a.w * k0.z;
        acc[i][1].x += a.x * k1.x - a.y * k1.y;  acc[i][1].y += a.x * k1.y + a.y * k1.x;
        acc[i][1].x += a.z * k1.z - a.w * k1.w;  acc[i][1].y += a.z * k1.w + a.w * k1.z;
      }
    }
    ushort2* op = OF + ((size_t)w * 256 + (h0 + g)) * 512;
#pragma unroll
    for (int i = 0; i < 4; ++i)
#pragma unroll
      for (int j = 0; j < 2; ++j)
        op[(bq + 4 * i) * 32 + fq + 16 * j] = make_ushort2(f2bf(acc[i][j].x), f2bf(acc[i][j].y));
  };

  load_regs(0); write_lds(0);
#pragma unroll
  for (int g = 0; g < PPW; ++g) {
    if (g + 1 < PPW) load_regs(g + 1);                // next point's globals in flight
    compute_store(g & 1, g);                          // same-wave DS ordering: no barrier
    if (g + 1 < PPW) write_lds((g + 1) & 1);
  }
}

// ---- K4: per (b,w,fg): 16 inverse column FFTs over h; store y' = h-63 in [0,128) ----
// T layout: [b][y'][w][f]  (f32)
__global__ __launch_bounds__(256) void k4_colifft(const ushort2* __restrict__ OF, float2* __restrict__ T) {
  __shared__ float2 lds[16 * 256];
  const int tid = threadIdx.x, r = tid >> 4, t = tid & 15;
  const int w = blockIdx.x, b = blockIdx.y, fg = blockIdx.z;
  const ushort2* ofp = OF + (size_t)w * 256 * 512 + b * 32 + fg * 16;
  for (int i = tid; i < Nn * 16; i += 256) {
    int h = i >> 4, fl = i & 15;
    ushort2 u = ofp[(size_t)h * 512 + fl];
    lds[IDX(fl, h)] = f2(bf2f(u.x), bf2f(u.y));
  }
  __syncthreads();
  float2 v[16];
#pragma unroll
  for (int j = 0; j < 16; ++j) v[j] = lds[IDX(r, t + 16 * j)];
  fft256_mid<1>(v, lds, r, t);
#pragma unroll
  for (int k2 = 3; k2 < 12; ++k2) lds[IDX(r, t + 16 * k2)] = v[k2];  // elems 48..191 cover 63..190
  __syncthreads();
  float2* tp = T + (size_t)b * Hh * WH * Ff + (size_t)w * Ff + fg * 16;
  for (int i = tid; i < Hh * 16; i += 256) {
    int yp = i >> 4, fl = i & 15;
    tp[(size_t)yp * WH * Ff + fl] = lds[IDX(fl, 63 + yp)];
  }
}

// ---- K5: per (b,y',fg): Hermitian-extend w-spectrum, inverse FFT, Re, scale, +bias, crop x ----
__global__ __launch_bounds__(256) void k5_rowifft(const float2* __restrict__ T, const float* __restrict__ bias,
                                                  float* __restrict__ out) {
  __shared__ float2 lds[16 * 256];
  const int tid = threadIdx.x, r = tid >> 4, t = tid & 15;
  const int yp = blockIdx.x, b = blockIdx.y, fg = blockIdx.z;
  const float2* tp = T + ((size_t)(b * Hh + yp) * WH) * Ff + fg * 16;
  for (int i = tid; i < WH * 16; i += 256) {
    int w = i >> 4, fl = i & 15;
    lds[IDX(fl, w)] = tp[(size_t)w * Ff + fl];
  }
  __syncthreads();
  float2 v[16];
#pragma unroll
  for (int n1 = 0; n1 < 16; ++n1) {
    const int c = t + 16 * n1;
    if (c <= 128) v[n1] = lds[IDX(r, c)];
    else { float2 z = lds[IDX(r, 256 - c)]; v[n1] = f2(z.x, -z.y); }
  }
  fft256_mid<1>(v, lds, r, t);
#pragma unroll
  for (int k2 = 3; k2 < 12; ++k2) lds[IDX(r, t + 16 * k2)] = v[k2];
  __syncthreads();
  const float sc = 1.f / 65536.f;
  const float bv = bias[fg * 16 + (tid & 15)];
  float* op = out + ((size_t)(b * Hh + yp) * Ww) * Ff + fg * 16;
  for (int i = tid; i < Ww * 16; i += 256) {
    int x = i >> 4, fl = i & 15;
    op[(size_t)x * Ff + fl] = lds[IDX(fl, 63 + x)].x * sc + bv;
  }
}

extern "C" void kernel_launch(void* const* d_in, const int* in_sizes, int n_in,
                              void* d_out, int out_size, void* d_ws, size_t ws_size,
                              hipStream_t stream) {
  const float* img  = (const float*)d_in[0];
  const float* kr   = (const float*)d_in[1];
  const float* ki   = (const float*)d_in[2];
  const float* bias = (const float*)d_in[3];
  float* out = (float*)d_out;

  char* ws = (char*)d_ws;
  // region layout (lifetime-overlapped, conservative offsets):
  //   [0, 67.6MB):     Fimg bf16 (K2->K3, 33.8MB used), later T f32 (K4->K5, 66MB used)
  //   [67.6MB, 203MB): OF bf16 (K3->K4, 67.6MB used); R f32 (K1->K2, 66MB) aliases its head
  const size_t szF = (size_t)Nn * WH * Bn * Cc * sizeof(float2);   // 67,633,152
  ushort2* Fimg = (ushort2*)ws;
  float2*  T    = (float2*)ws;
  ushort2* OF   = (ushort2*)(ws + szF);
  float2*  R    = (float2*)(ws + szF);

  k1_rowfft <<<dim3(Hh, Bn),      256, 0, stream>>>(img, R);
  k2_colfft <<<dim3(WH, Bn),      256, 0, stream>>>(R, Fimg);
  k3_mul    <<<dim3(WH, Nn / GP), 256, 0, stream>>>(Fimg, kr, ki, OF);
  k4_colifft<<<dim3(WH, Bn, 2),   256, 0, stream>>>(OF, T);
  k5_rowifft<<<dim3(Hh, Bn, 2),   256, 0, stream>>>(T, bias, out);
}